// Round 1
// baseline (1279.183 us; speedup 1.0000x reference)
//
#include <hip/hip_runtime.h>
#include <math.h>

#define NN 512           // nodes
#define BB 128           // batch
#define CIN 66           // F_IN + C_OUT
#define QQ (BB*CIN)      // 8448 columns in diffusion GEMM
#define RR (NN*BB)       // 65536 rows in projection GEMM
#define SX (NN*QQ)       // 4325376 floats per (n,b,c) tensor
#define SRU (NN*BB*128)  // 8388608
#define SCP (NN*BB*64)   // 4194304

// ---------- adp = row-softmax(relu(nv1 @ nv2)) ----------
__global__ __launch_bounds__(512) void adp_kernel(const float* __restrict__ nv1,
                                                  const float* __restrict__ nv2,
                                                  float* __restrict__ adp) {
    int n = blockIdx.x;
    int m = threadIdx.x;
    float z = 0.f;
#pragma unroll
    for (int k = 0; k < 10; k++) z = fmaf(nv1[n * 10 + k], nv2[k * NN + m], z);
    z = fmaxf(z, 0.f);

    __shared__ float sred[8];
    int wid  = threadIdx.x >> 6;
    int lane = threadIdx.x & 63;

    float v = z;
#pragma unroll
    for (int off = 32; off; off >>= 1) v = fmaxf(v, __shfl_down(v, off, 64));
    if (lane == 0) sred[wid] = v;
    __syncthreads();
    float zmax = sred[0];
#pragma unroll
    for (int i = 1; i < 8; i++) zmax = fmaxf(zmax, sred[i]);

    float e = __expf(z - zmax);
    __syncthreads();
    v = e;
#pragma unroll
    for (int off = 32; off; off >>= 1) v += __shfl_down(v, off, 64);
    if (lane == 0) sred[wid] = v;
    __syncthreads();
    float tot = 0.f;
#pragma unroll
    for (int i = 0; i < 8; i++) tot += sred[i];

    adp[n * NN + m] = e / tot;
}

// ---------- build xt[n,b,c] = concat(input, (r*)state) ----------
__global__ void build_x_kernel(const float* __restrict__ inp,
                               const float* __restrict__ st,
                               const float* __restrict__ ru,   // null for layer 1
                               float* __restrict__ xt) {
    int idx = blockIdx.x * 256 + threadIdx.x;
    if (idx >= SX) return;
    int n   = idx / QQ;
    int rem = idx - n * QQ;
    int b   = rem / CIN;
    int c   = rem - b * CIN;
    float v;
    if (c < 2) {
        v = inp[(b * NN + n) * 2 + c];
    } else {
        v = st[((b * NN + n) << 6) + (c - 2)];
        if (ru) v *= ru[((n * BB + b) << 7) + (c - 2)];   // r part of value
    }
    xt[idx] = v;
}

// ---------- diffusion GEMM: C[m,q] = sum_n A[n,m] * X[n,q] ----------
// M=512, Q=8448, K=512.  Tile 64(m) x 128(q), BK=16, 256 threads, 4x8/thread.
__global__ __launch_bounds__(256) void gemm_diff(const float* __restrict__ A,
                                                 const float* __restrict__ X,
                                                 float* __restrict__ C) {
    __shared__ float As[16][68];    // As[k][m], padded
    __shared__ float Xs[16][132];   // Xs[k][q], padded
    const int m0  = blockIdx.y * 64;
    const int q0  = blockIdx.x * 128;
    const int tid = threadIdx.x;
    const int mg  = tid >> 4;       // 0..15 -> 4 m each
    const int qg  = tid & 15;       // 0..15 -> 8 q each
    const int lk  = tid >> 4;       // A-load row
    const int lm  = (tid & 15) << 2;

    float acc[4][8] = {};

    for (int k0 = 0; k0 < NN; k0 += 16) {
        *(float4*)&As[lk][lm] = *(const float4*)(A + (size_t)(k0 + lk) * NN + m0 + lm);
#pragma unroll
        for (int l = 0; l < 2; l++) {
            int idx = tid + l * 256;
            int kk  = idx >> 5;
            int q4  = (idx & 31) << 2;
            *(float4*)&Xs[kk][q4] = *(const float4*)(X + (size_t)(k0 + kk) * QQ + q0 + q4);
        }
        __syncthreads();
#pragma unroll
        for (int k = 0; k < 16; k++) {
            float a[4], x[8];
            *(float4*)a      = *(float4*)&As[k][mg << 2];
            *(float4*)&x[0]  = *(float4*)&Xs[k][qg << 3];
            *(float4*)&x[4]  = *(float4*)&Xs[k][(qg << 3) + 4];
#pragma unroll
            for (int i = 0; i < 4; i++)
#pragma unroll
                for (int j = 0; j < 8; j++)
                    acc[i][j] = fmaf(a[i], x[j], acc[i][j]);
        }
        __syncthreads();
    }
#pragma unroll
    for (int i = 0; i < 4; i++) {
        float* dst = C + (size_t)(m0 + (mg << 2) + i) * QQ + q0 + (qg << 3);
        *(float4*)dst       = *(float4*)&acc[i][0];
        *(float4*)(dst + 4) = *(float4*)&acc[i][4];
    }
}

// ---------- projection GEMM slab: Out[r,j] (+)= sum_c Xin[r,c]*W[c,j] ----------
// MODE 0: Out = acc + bias   MODE 1: Out += acc   MODE 2: Out = sigmoid(Out + acc)
template <int COUT, int MODE>
__global__ __launch_bounds__(256) void gemm_proj(const float* __restrict__ Xin,
                                                 const float* __restrict__ W,
                                                 const float* __restrict__ bias,
                                                 float* __restrict__ Out) {
    const int K     = CIN;          // 66
    const int JT    = COUT / 4;     // thread-cols (32 or 16)
    const int RT    = 256 / JT;     // thread-row groups (8 or 16)
    const int BROWS = RT * 8;       // rows per block (64 or 128)

    __shared__ float Ws[K * COUT];
    __shared__ float Xs[BROWS * K];

    const int    tid = threadIdx.x;
    const size_t r0  = (size_t)blockIdx.x * BROWS;

    for (int i = tid; i < K * COUT / 4; i += 256)
        *(float4*)&Ws[i * 4] = *(const float4*)(W + i * 4);
    for (int i = tid; i < BROWS * K / 4; i += 256)
        *(float4*)&Xs[i * 4] = *(const float4*)(Xin + r0 * K + i * 4);
    __syncthreads();

    const int jt = tid % JT;
    const int rt = tid / JT;
    float acc[8][4] = {};

#pragma unroll 2
    for (int k = 0; k < K; k++) {
        float w[4];
        *(float4*)w = *(float4*)&Ws[k * COUT + jt * 4];
#pragma unroll
        for (int i = 0; i < 8; i++) {
            float xv = Xs[(rt * 8 + i) * K + k];
#pragma unroll
            for (int j = 0; j < 4; j++)
                acc[i][j] = fmaf(xv, w[j], acc[i][j]);
        }
    }

#pragma unroll
    for (int i = 0; i < 8; i++) {
        float* dst = Out + (r0 + rt * 8 + i) * COUT + jt * 4;
        float4 v   = *(float4*)&acc[i][0];
        if (MODE == 0) {
            float4 bj = *(const float4*)(bias + jt * 4);
            v.x += bj.x; v.y += bj.y; v.z += bj.z; v.w += bj.w;
        } else {
            float4 p = *(const float4*)dst;
            v.x += p.x; v.y += p.y; v.z += p.z; v.w += p.w;
        }
        if (MODE == 2) {
            v.x = 1.f / (1.f + __expf(-v.x));
            v.y = 1.f / (1.f + __expf(-v.y));
            v.z = 1.f / (1.f + __expf(-v.z));
            v.w = 1.f / (1.f + __expf(-v.w));
        }
        *(float4*)dst = v;
    }
}

// ---------- final: out[b,n,j] = u*state + (1-u)*tanh(cpre) ----------
__global__ void final_kernel(const float* __restrict__ st,
                             const float* __restrict__ ru,
                             const float* __restrict__ cp,
                             float* __restrict__ out) {
    int idx = blockIdx.x * 256 + threadIdx.x;
    if (idx >= BB * NN * 64) return;
    int b   = idx >> 15;
    int rem = idx & 32767;
    int n   = rem >> 6;
    int j   = idx & 63;
    float u = ru[((n * BB + b) << 7) + 64 + j];
    float s = st[idx];
    float c = tanhf(cp[((n * BB + b) << 6) + j]);
    out[idx] = u * s + (1.f - u) * c;
}

extern "C" void kernel_launch(void* const* d_in, const int* in_sizes, int n_in,
                              void* d_out, int out_size, void* d_ws, size_t ws_size,
                              hipStream_t stream) {
    const float* input = (const float*)d_in[0];
    const float* state = (const float*)d_in[1];
    const float* A0    = (const float*)d_in[2];
    const float* A1    = (const float*)d_in[3];
    const float* nv1_1 = (const float*)d_in[4];
    const float* nv2_1 = (const float*)d_in[5];
    const float* W1    = (const float*)d_in[6];
    const float* b1    = (const float*)d_in[7];
    const float* nv1_2 = (const float*)d_in[8];
    const float* nv2_2 = (const float*)d_in[9];
    const float* W2    = (const float*)d_in[10];
    const float* b2    = (const float*)d_in[11];
    float* out = (float*)d_out;

    float* XT   = (float*)d_ws;
    float* X1   = XT + SX;
    float* X2   = X1 + SX;
    float* RU   = X2 + SX;
    float* CP   = RU + SRU;
    float* ADP1 = CP + SCP;
    float* ADP2 = ADP1 + NN * NN;

    dim3 gDiff(QQ / 128, NN / 64);

    adp_kernel<<<NN, NN, 0, stream>>>(nv1_1, nv2_1, ADP1);
    adp_kernel<<<NN, NN, 0, stream>>>(nv1_2, nv2_2, ADP2);
    build_x_kernel<<<(SX + 255) / 256, 256, 0, stream>>>(input, state, nullptr, XT);

    // ---- layer 1 (COUT=128): value = sigmoid(h @ W1 + b1) ----
    gemm_proj<128, 0><<<RR / 64, 256, 0, stream>>>(XT, W1, b1, RU);
    const float* sup1[3] = {A0, A1, ADP1};
    for (int s = 0; s < 3; s++) {
        gemm_diff<<<gDiff, 256, 0, stream>>>(sup1[s], XT, X1);
        gemm_proj<128, 1><<<RR / 64, 256, 0, stream>>>(X1, W1 + (66 + s * 132) * 128, b1, RU);
        gemm_diff<<<gDiff, 256, 0, stream>>>(sup1[s], X1, X2);
        if (s < 2)
            gemm_proj<128, 1><<<RR / 64, 256, 0, stream>>>(X2, W1 + (132 + s * 132) * 128, b1, RU);
        else
            gemm_proj<128, 2><<<RR / 64, 256, 0, stream>>>(X2, W1 + (132 + s * 132) * 128, b1, RU);
    }

    // ---- x2 = concat(input, r*state) ----
    build_x_kernel<<<(SX + 255) / 256, 256, 0, stream>>>(input, state, RU, XT);

    // ---- layer 2 (COUT=64): c_pre = h2 @ W2 + b2 ----
    gemm_proj<64, 0><<<RR / 128, 256, 0, stream>>>(XT, W2, b2, CP);
    const float* sup2[3] = {A0, A1, ADP2};
    for (int s = 0; s < 3; s++) {
        gemm_diff<<<gDiff, 256, 0, stream>>>(sup2[s], XT, X1);
        gemm_proj<64, 1><<<RR / 128, 256, 0, stream>>>(X1, W2 + (66 + s * 132) * 64, b2, CP);
        gemm_diff<<<gDiff, 256, 0, stream>>>(sup2[s], X1, X2);
        gemm_proj<64, 1><<<RR / 128, 256, 0, stream>>>(X2, W2 + (132 + s * 132) * 64, b2, CP);
    }

    final_kernel<<<(BB * NN * 64 + 255) / 256, 256, 0, stream>>>(state, RU, CP, out);
}

// Round 2
// 557.909 us; speedup vs baseline: 2.2928x; 2.2928x over previous
//
#include <hip/hip_runtime.h>
#include <math.h>

#define NN 512
#define BB 128
#define CIN 66
#define QQ (BB*CIN)            // 8448
#define QN ((size_t)QQ*NN)     // 4325376 elements per (q,n) tensor
#define AN ((size_t)NN*NN)

typedef unsigned short ushort_t;
typedef __attribute__((ext_vector_type(8))) short short8;
typedef __attribute__((ext_vector_type(4))) float f32x4;
typedef __attribute__((ext_vector_type(4))) unsigned short us4;

__device__ __forceinline__ ushort_t f2bf(float f) {
    unsigned u = __float_as_uint(f);
    u += 0x7FFF + ((u >> 16) & 1);          // round-to-nearest-even
    return (ushort_t)(u >> 16);
}
__device__ __forceinline__ float bf2f(ushort_t h) {
    return __uint_as_float(((unsigned)h) << 16);
}
__device__ __forceinline__ void split_bf(float f, ushort_t& hi, ushort_t& lo) {
    hi = f2bf(f);
    lo = f2bf(f - bf2f(hi));
}
__device__ __forceinline__ void gload_lds16(const void* g, void* l) {
    __builtin_amdgcn_global_load_lds(
        (const __attribute__((address_space(1))) unsigned*)g,
        (__attribute__((address_space(3))) unsigned*)l, 16, 0, 0);
}

// ---------- adp = row-softmax(relu(nv1 @ nv2)) ----------
__global__ __launch_bounds__(512) void adp_kernel(const float* __restrict__ nv1,
                                                  const float* __restrict__ nv2,
                                                  float* __restrict__ adp) {
    int n = blockIdx.x;
    int m = threadIdx.x;
    float z = 0.f;
#pragma unroll
    for (int k = 0; k < 10; k++) z = fmaf(nv1[n * 10 + k], nv2[k * NN + m], z);
    z = fmaxf(z, 0.f);

    __shared__ float sred[8];
    int wid  = threadIdx.x >> 6;
    int lane = threadIdx.x & 63;

    float v = z;
#pragma unroll
    for (int off = 32; off; off >>= 1) v = fmaxf(v, __shfl_down(v, off, 64));
    if (lane == 0) sred[wid] = v;
    __syncthreads();
    float zmax = sred[0];
#pragma unroll
    for (int i = 1; i < 8; i++) zmax = fmaxf(zmax, sred[i]);

    float e = __expf(z - zmax);
    __syncthreads();
    v = e;
#pragma unroll
    for (int off = 32; off; off >>= 1) v += __shfl_down(v, off, 64);
    if (lane == 0) sred[wid] = v;
    __syncthreads();
    float tot = 0.f;
#pragma unroll
    for (int i = 0; i < 8; i++) tot += sred[i];

    adp[n * NN + m] = e / tot;
}

// ---------- transpose + bf16-split the 4 supports: Ahi/Alo[s][m][k] = split(src[k][m]) ----------
__global__ __launch_bounds__(256) void asplit_kernel(const float* __restrict__ A0,
                                                     const float* __restrict__ A1,
                                                     const float* __restrict__ P1,
                                                     const float* __restrict__ P2,
                                                     ushort_t* __restrict__ Ahi,
                                                     ushort_t* __restrict__ Alo) {
    __shared__ float t[32][33];
    int s = blockIdx.z;
    const float* src = (s == 0) ? A0 : (s == 1) ? A1 : (s == 2) ? P1 : P2;
    int m0 = blockIdx.x * 32, k0 = blockIdx.y * 32;
    int tx = threadIdx.x & 31, ty = threadIdx.x >> 5;   // 32 x 8
#pragma unroll
    for (int r = 0; r < 32; r += 8)
        t[ty + r][tx] = src[(size_t)(k0 + ty + r) * NN + m0 + tx];
    __syncthreads();
#pragma unroll
    for (int r = 0; r < 32; r += 8) {
        int m = m0 + ty + r, k = k0 + tx;
        float v = t[tx][ty + r];
        ushort_t h, l; split_bf(v, h, l);
        size_t o = ((size_t)s * NN + m) * NN + k;
        Ahi[o] = h; Alo[o] = l;
    }
}

// ---------- build XT[q=(b,c)][n] bf16 hi/lo from input+state ----------
__global__ __launch_bounds__(256) void buildx_kernel(const float* __restrict__ inp,
                                                     const float* __restrict__ st,
                                                     ushort_t* __restrict__ Xhi,
                                                     ushort_t* __restrict__ Xlo) {
    __shared__ float S[64][65];
    __shared__ float I[64][2];
    int b = blockIdx.y, n0 = blockIdx.x * 64;
    int tid = threadIdx.x;
    int j = tid & 63;
    for (int r = tid >> 6; r < 64; r += 4)
        S[r][j] = st[((size_t)b * NN + n0 + r) * 64 + j];
    if (tid < 128)
        I[tid >> 1][tid & 1] = inp[((size_t)b * NN + n0 + (tid >> 1)) * 2 + (tid & 1)];
    __syncthreads();
    int ln = tid & 63, cq = tid >> 6;
    for (int c = cq; c < CIN; c += 4) {
        float v = (c < 2) ? I[ln][c] : S[ln][c - 2];
        ushort_t h, l; split_bf(v, h, l);
        size_t o = ((size_t)b * CIN + c) * NN + n0 + ln;
        Xhi[o] = h; Xlo[o] = l;
    }
}

// ---------- diffusion GEMM (MFMA, split-bf16): Y[q][m] = sum_n A[n][m] X[q][n] ----------
// Aop[m][k] (pre-transposed), X [q][n]. 128x128 tile, BK=32, 256 thr = 2x2 waves.
__global__ __launch_bounds__(256) void diff_mfma(const ushort_t* __restrict__ Ahi,
                                                 const ushort_t* __restrict__ Alo,
                                                 const ushort_t* __restrict__ Xhi,
                                                 const ushort_t* __restrict__ Xlo,
                                                 ushort_t* __restrict__ Yhi,
                                                 ushort_t* __restrict__ Ylo,
                                                 size_t x_stride, int s2) {
    __shared__ ushort_t sAh[128 * 32];
    __shared__ ushort_t sAl[128 * 32];
    __shared__ ushort_t sXh[128 * 32];
    __shared__ ushort_t sXl[128 * 32];
    const int tid  = threadIdx.x;
    const int lane = tid & 63, w = tid >> 6;
    const int quad = lane >> 4, l15 = lane & 15;
    const int q0 = blockIdx.x * 128, m0 = blockIdx.y * 128;
    const int sup = (blockIdx.z < 2) ? blockIdx.z : s2;
    const ushort_t* Ah = Ahi + (size_t)sup * AN;
    const ushort_t* Al = Alo + (size_t)sup * AN;
    const ushort_t* Xh = Xhi + (size_t)blockIdx.z * x_stride;
    const ushort_t* Xl = Xlo + (size_t)blockIdx.z * x_stride;
    const int wm = w & 1, wq = w >> 1;

    f32x4 acc[4][4] = {};

    for (int k0 = 0; k0 < NN; k0 += 32) {
        __syncthreads();
#pragma unroll
        for (int p = 0; p < 2; p++) {
            int l2  = p * 64 + lane;
            int row = w * 32 + (l2 >> 2);
            int kk  = (l2 & 3) * 8;
            int loff = row * 32 + kk;
            gload_lds16(Ah + (size_t)(m0 + row) * NN + k0 + kk, sAh + loff);
            gload_lds16(Al + (size_t)(m0 + row) * NN + k0 + kk, sAl + loff);
            gload_lds16(Xh + (size_t)(q0 + row) * NN + k0 + kk, sXh + loff);
            gload_lds16(Xl + (size_t)(q0 + row) * NN + k0 + kk, sXl + loff);
        }
        __syncthreads();
        short8 ah[4], al[4], xh[4], xl[4];
#pragma unroll
        for (int t = 0; t < 4; t++) {
            int arow = wm * 64 + t * 16 + l15;
            int xrow = wq * 64 + t * 16 + l15;
            ah[t] = *(const short8*)&sAh[arow * 32 + quad * 8];
            al[t] = *(const short8*)&sAl[arow * 32 + quad * 8];
            xh[t] = *(const short8*)&sXh[xrow * 32 + quad * 8];
            xl[t] = *(const short8*)&sXl[xrow * 32 + quad * 8];
        }
#pragma unroll
        for (int mt = 0; mt < 4; mt++)
#pragma unroll
            for (int qt = 0; qt < 4; qt++) {
                acc[mt][qt] = __builtin_amdgcn_mfma_f32_16x16x32_bf16(ah[mt], xh[qt], acc[mt][qt], 0, 0, 0);
                acc[mt][qt] = __builtin_amdgcn_mfma_f32_16x16x32_bf16(ah[mt], xl[qt], acc[mt][qt], 0, 0, 0);
                acc[mt][qt] = __builtin_amdgcn_mfma_f32_16x16x32_bf16(al[mt], xh[qt], acc[mt][qt], 0, 0, 0);
            }
    }

    ushort_t* Yh = Yhi + (size_t)blockIdx.z * QN;
    ushort_t* Yl = Ylo + (size_t)blockIdx.z * QN;
#pragma unroll
    for (int mt = 0; mt < 4; mt++)
#pragma unroll
        for (int qt = 0; qt < 4; qt++) {
            int q  = q0 + wq * 64 + qt * 16 + l15;
            int mb = m0 + wm * 64 + mt * 16 + quad * 4;
            us4 h4, l4;
#pragma unroll
            for (int r = 0; r < 4; r++) {
                ushort_t h, l; split_bf(acc[mt][qt][r], h, l);
                h4[r] = h; l4[r] = l;
            }
            *(us4*)&Yh[(size_t)q * NN + mb] = h4;
            *(us4*)&Yl[(size_t)q * NN + mb] = l4;
        }
}

// ---------- fused projection: out = act( sum_slabs X_s @ W_s + b ) ----------
// LAYER 1: sigmoid; r-part writes r*state back into XT slab (c>=2); u-part -> U.
// LAYER 2: tanh + gate + final output.
template <int COUT, int LAYER>
__global__ __launch_bounds__(256) void proj_kernel(
    const ushort_t* XThi, const ushort_t* XTlo,
    const ushort_t* __restrict__ Y1hi, const ushort_t* __restrict__ Y1lo,
    const ushort_t* __restrict__ Y2hi, const ushort_t* __restrict__ Y2lo,
    const float* __restrict__ W, const float* __restrict__ bias,
    ushort_t* XThiw, ushort_t* XTlow,
    float* U, const float* __restrict__ state, float* __restrict__ out) {
    constexpr int JT  = COUT / 4;     // 32 or 16 threads across cols
    constexpr int RT  = 256 / JT;     // 8 or 16 row groups
    constexpr int RPT = 64 / RT;      // 8 or 4 rows per thread

    __shared__ float Ws[66 * COUT];
    __shared__ float Xs[64 * 68];
    const int b = blockIdx.y, n0 = blockIdx.x * 64;
    const int tid = threadIdx.x;
    const int jt = tid % JT, rt = tid / JT;
    float acc[RPT][4] = {};

    for (int s = 0; s < 7; s++) {
        const ushort_t *hi, *lo; int woff;
        if (s == 0)      { hi = XThi; lo = XTlo; woff = 0; }
        else if (s & 1)  { int sp = s >> 1;      hi = Y1hi + (size_t)sp * QN; lo = Y1lo + (size_t)sp * QN; woff = 66 + sp * 132; }
        else             { int sp = (s >> 1) - 1; hi = Y2hi + (size_t)sp * QN; lo = Y2lo + (size_t)sp * QN; woff = 132 + sp * 132; }
        __syncthreads();
        for (int i = tid; i < 66 * COUT / 4; i += 256)
            *(f32x4*)&Ws[i * 4] = *(const f32x4*)&W[(size_t)woff * COUT + i * 4];
        {
            int l4 = tid & 15, c16 = tid >> 4;
            for (int c = c16; c < CIN; c += 16) {
                size_t gi = ((size_t)b * CIN + c) * NN + n0 + l4 * 4;
                us4 h4 = *(const us4*)&hi[gi];
                us4 g4 = *(const us4*)&lo[gi];
#pragma unroll
                for (int jj = 0; jj < 4; jj++)
                    Xs[(l4 * 4 + jj) * 68 + c] = bf2f(h4[jj]) + bf2f(g4[jj]);
            }
        }
        __syncthreads();
        for (int k = 0; k < 64; k += 4) {
            f32x4 x4[RPT];
#pragma unroll
            for (int i = 0; i < RPT; i++)
                x4[i] = *(const f32x4*)&Xs[(rt * RPT + i) * 68 + k];
#pragma unroll
            for (int kk = 0; kk < 4; kk++) {
                f32x4 w4 = *(const f32x4*)&Ws[(k + kk) * COUT + jt * 4];
#pragma unroll
                for (int i = 0; i < RPT; i++) {
                    acc[i][0] = fmaf(x4[i][kk], w4[0], acc[i][0]);
                    acc[i][1] = fmaf(x4[i][kk], w4[1], acc[i][1]);
                    acc[i][2] = fmaf(x4[i][kk], w4[2], acc[i][2]);
                    acc[i][3] = fmaf(x4[i][kk], w4[3], acc[i][3]);
                }
            }
        }
        for (int k = 64; k < 66; k++) {
            f32x4 w4 = *(const f32x4*)&Ws[k * COUT + jt * 4];
#pragma unroll
            for (int i = 0; i < RPT; i++) {
                float xv = Xs[(rt * RPT + i) * 68 + k];
                acc[i][0] = fmaf(xv, w4[0], acc[i][0]);
                acc[i][1] = fmaf(xv, w4[1], acc[i][1]);
                acc[i][2] = fmaf(xv, w4[2], acc[i][2]);
                acc[i][3] = fmaf(xv, w4[3], acc[i][3]);
            }
        }
    }

    f32x4 bj = *(const f32x4*)&bias[jt * 4];
#pragma unroll
    for (int i = 0; i < RPT; i++) {
        int n = n0 + rt * RPT + i;
        f32x4 v;
#pragma unroll
        for (int jj = 0; jj < 4; jj++) v[jj] = acc[i][jj] + bj[jj];
        if (LAYER == 1) {
#pragma unroll
            for (int jj = 0; jj < 4; jj++) v[jj] = 1.f / (1.f + __expf(-v[jj]));
            if (jt < 16) {   // r-part: write r*state into XT rows c = 2+j
                f32x4 st4 = *(const f32x4*)&state[((size_t)b * NN + n) * 64 + jt * 4];
#pragma unroll
                for (int jj = 0; jj < 4; jj++) {
                    float x2 = v[jj] * st4[jj];
                    ushort_t h, l; split_bf(x2, h, l);
                    size_t o = ((size_t)b * CIN + 2 + jt * 4 + jj) * NN + n;
                    XThiw[o] = h; XTlow[o] = l;
                }
            } else {         // u-part
                *(f32x4*)&U[((size_t)b * NN + n) * 64 + (jt - 16) * 4] = v;
            }
        } else {
            f32x4 u4  = *(const f32x4*)&U[((size_t)b * NN + n) * 64 + jt * 4];
            f32x4 st4 = *(const f32x4*)&state[((size_t)b * NN + n) * 64 + jt * 4];
            f32x4 o4;
#pragma unroll
            for (int jj = 0; jj < 4; jj++) {
                float c = tanhf(v[jj]);
                o4[jj] = u4[jj] * st4[jj] + (1.f - u4[jj]) * c;
            }
            *(f32x4*)&out[((size_t)b * NN + n) * 64 + jt * 4] = o4;
        }
    }
}

extern "C" void kernel_launch(void* const* d_in, const int* in_sizes, int n_in,
                              void* d_out, int out_size, void* d_ws, size_t ws_size,
                              hipStream_t stream) {
    const float* input = (const float*)d_in[0];
    const float* state = (const float*)d_in[1];
    const float* A0    = (const float*)d_in[2];
    const float* A1    = (const float*)d_in[3];
    const float* nv1_1 = (const float*)d_in[4];
    const float* nv2_1 = (const float*)d_in[5];
    const float* W1    = (const float*)d_in[6];
    const float* b1    = (const float*)d_in[7];
    const float* nv1_2 = (const float*)d_in[8];
    const float* nv2_2 = (const float*)d_in[9];
    const float* W2    = (const float*)d_in[10];
    const float* b2    = (const float*)d_in[11];
    float* out = (float*)d_out;

    char* p = (char*)d_ws;
    auto alloc = [&](size_t bytes) { void* r = (void*)p; p += (bytes + 255) & ~(size_t)255; return r; };
    float*    ADP1 = (float*)alloc(AN * 4);
    float*    ADP2 = (float*)alloc(AN * 4);
    ushort_t* Ahi  = (ushort_t*)alloc(4 * AN * 2);
    ushort_t* Alo  = (ushort_t*)alloc(4 * AN * 2);
    ushort_t* XThi = (ushort_t*)alloc(QN * 2);
    ushort_t* XTlo = (ushort_t*)alloc(QN * 2);
    ushort_t* Y1hi = (ushort_t*)alloc(3 * QN * 2);
    ushort_t* Y1lo = (ushort_t*)alloc(3 * QN * 2);
    ushort_t* Y2hi = (ushort_t*)alloc(3 * QN * 2);
    ushort_t* Y2lo = (ushort_t*)alloc(3 * QN * 2);
    float*    U    = (float*)alloc((size_t)NN * BB * 64 * 4);

    adp_kernel<<<NN, NN, 0, stream>>>(nv1_1, nv2_1, ADP1);
    adp_kernel<<<NN, NN, 0, stream>>>(nv1_2, nv2_2, ADP2);
    asplit_kernel<<<dim3(16, 16, 4), 256, 0, stream>>>(A0, A1, ADP1, ADP2, Ahi, Alo);
    buildx_kernel<<<dim3(8, BB), 256, 0, stream>>>(input, state, XThi, XTlo);

    dim3 gd(QQ / 128, 4, 3);
    // layer 1
    diff_mfma<<<gd, 256, 0, stream>>>(Ahi, Alo, XThi, XTlo, Y1hi, Y1lo, 0, 2);
    diff_mfma<<<gd, 256, 0, stream>>>(Ahi, Alo, Y1hi, Y1lo, Y2hi, Y2lo, QN, 2);
    proj_kernel<128, 1><<<dim3(8, BB), 256, 0, stream>>>(XThi, XTlo, Y1hi, Y1lo, Y2hi, Y2lo,
                                                         W1, b1, XThi, XTlo, U, state, nullptr);
    // layer 2 (XT rows c>=2 now hold r*state; rows c<2 unchanged)
    diff_mfma<<<gd, 256, 0, stream>>>(Ahi, Alo, XThi, XTlo, Y1hi, Y1lo, 0, 3);
    diff_mfma<<<gd, 256, 0, stream>>>(Ahi, Alo, Y1hi, Y1lo, Y2hi, Y2lo, QN, 3);
    proj_kernel<64, 2><<<dim3(8, BB), 256, 0, stream>>>(XThi, XTlo, Y1hi, Y1lo, Y2hi, Y2lo,
                                                        W2, b2, nullptr, nullptr, U, state, out);
}